// Round 2
// baseline (91.875 us; speedup 1.0000x reference)
//
#include <hip/hip_runtime.h>

#define GHMR_MU   0.02f
#define GHMR_BINS 30
#define GHMR_MAXBLK 2048

// ---------------------------------------------------------------------------
// Kernel 1: single pass over all elements.
//   per-bin: sum of loss over valid elements, count of valid elements.
//   bin 29 (~96% of elements) accumulates in registers; rare bins via LDS.
//   Tail: one coalesced 256B partial store per block (NO global atomics).
// ---------------------------------------------------------------------------
__global__ __launch_bounds__(256) void ghmr_hist(
    const float4* __restrict__ pred,
    const float4* __restrict__ target,
    const float4* __restrict__ lw,
    float* __restrict__ part,   // [nblk][64]: [0..29]=sums, [32..61]=counts
    int n4)
{
    __shared__ float        s_sum[GHMR_BINS];
    __shared__ unsigned int s_cnt[GHMR_BINS];

    const int tid = threadIdx.x;
    if (tid < GHMR_BINS) { s_sum[tid] = 0.0f; s_cnt[tid] = 0u; }
    __syncthreads();

    const float mu2 = GHMR_MU * GHMR_MU;

    float        sum29 = 0.0f;   // fast-path accumulator (bin 29)
    unsigned int cnt29 = 0u;

    const int stride = gridDim.x * blockDim.x;
    for (int i = blockIdx.x * blockDim.x + tid; i < n4; i += stride) {
        float4 p = pred[i];
        float4 t = target[i];
        float4 w = lw[i];
#pragma unroll
        for (int j = 0; j < 4; ++j) {
            float pj = (&p.x)[j];
            float tj = (&t.x)[j];
            float wj = (&w.x)[j];

            float d    = pj - tj;
            float d2   = fmaf(d, d, mu2);
            float r    = sqrtf(d2);
            float loss = r - GHMR_MU;
            float g    = fabsf(d) * rsqrtf(d2);   // in [0,1)
            int   idx  = (int)(g * (float)GHMR_BINS);
            idx        = (idx > GHMR_BINS - 1) ? (GHMR_BINS - 1) : idx;
            bool valid = (wj > 0.0f);

            if (valid) {
                if (idx == GHMR_BINS - 1) {
                    sum29 += loss;
                    cnt29 += 1u;
                } else {
                    atomicAdd(&s_sum[idx], loss);
                    atomicAdd(&s_cnt[idx], 1u);
                }
            }
        }
    }

    // wave-level reduction of the fast-path accumulators (wave = 64 lanes)
    for (int off = 32; off > 0; off >>= 1) {
        sum29 += __shfl_down(sum29, off);
        cnt29 += (unsigned int)__shfl_down((int)cnt29, off);
    }
    if ((tid & 63) == 0) {
        atomicAdd(&s_sum[GHMR_BINS - 1], sum29);
        atomicAdd(&s_cnt[GHMR_BINS - 1], cnt29);
    }
    __syncthreads();

    // block -> global partials: one coalesced 256B store, no atomics.
    if (tid < GHMR_BINS) {
        part[blockIdx.x * 64 + tid] = s_sum[tid];
    } else if (tid >= 32 && tid < 32 + GHMR_BINS) {
        // counts as float: per-bin totals < 2^24, exact in fp32
        part[blockIdx.x * 64 + tid] = (float)s_cnt[tid - 32];
    }
}

// ---------------------------------------------------------------------------
// Kernel 2: finalize.  result = (1/n) * sum_b  S_b / max(c_b, 1)
// (tot cancels algebraically in the reference expression.)
// One block, 1024 threads = 16 waves; wave w reduces bins w and w+16.
// ---------------------------------------------------------------------------
__global__ __launch_bounds__(1024) void ghmr_final(
    const float* __restrict__ part, float* __restrict__ out, int nblk)
{
    __shared__ float terms[32];
    __shared__ float nz[32];

    const int wave = threadIdx.x >> 6;   // 0..15
    const int lane = threadIdx.x & 63;

    if (threadIdx.x < 32) { terms[threadIdx.x] = 0.0f; nz[threadIdx.x] = 0.0f; }
    __syncthreads();

    for (int b = wave; b < GHMR_BINS; b += 16) {
        float s = 0.0f, c = 0.0f;
        for (int blk = lane; blk < nblk; blk += 64) {
            s += part[blk * 64 + b];
            c += part[blk * 64 + 32 + b];
        }
        for (int off = 32; off > 0; off >>= 1) {
            s += __shfl_down(s, off);
            c += __shfl_down(c, off);
        }
        if (lane == 0) {
            terms[b] = s / fmaxf(c, 1.0f);
            nz[b]    = (c > 0.0f) ? 1.0f : 0.0f;
        }
    }
    __syncthreads();

    if (threadIdx.x < 64) {
        float t = (threadIdx.x < GHMR_BINS) ? terms[threadIdx.x] : 0.0f;
        float z = (threadIdx.x < GHMR_BINS) ? nz[threadIdx.x]    : 0.0f;
        for (int off = 32; off > 0; off >>= 1) {
            t += __shfl_down(t, off);
            z += __shfl_down(z, off);
        }
        if (threadIdx.x == 0) out[0] = t / fmaxf(z, 1.0f);
    }
}

// ---------------------------------------------------------------------------
extern "C" void kernel_launch(void* const* d_in, const int* in_sizes, int n_in,
                              void* d_out, int out_size, void* d_ws, size_t ws_size,
                              hipStream_t stream) {
    const float4* pred   = (const float4*)d_in[0];
    const float4* target = (const float4*)d_in[1];
    const float4* lw     = (const float4*)d_in[2];

    int n  = in_sizes[0];      // B*C = 16,777,216 (divisible by 4)
    int n4 = n / 4;

    float* part = (float*)d_ws;   // nblk * 64 floats

    // cap block count by available workspace (256B per block)
    size_t max_blk_ws = ws_size / (64 * sizeof(float));
    int nblk = GHMR_MAXBLK;
    if ((size_t)nblk > max_blk_ws) nblk = (int)max_blk_ws;
    if (nblk < 1) nblk = 1;

    ghmr_hist<<<nblk, 256, 0, stream>>>(pred, target, lw, part, n4);
    ghmr_final<<<1, 1024, 0, stream>>>(part, (float*)d_out, nblk);
}

// Round 3
// 79.451 us; speedup vs baseline: 1.1564x; 1.1564x over previous
//
#include <hip/hip_runtime.h>

#define MU_F    0.02f
#define MU2_F   (0.02f*0.02f)
#define T29_F   5.7016947e-3f      // MU2 * 841/59: d^2 below this => bin < 29
#define BINS    30
#define ROWS    62                 // 0..29 sums, 30..59 counts, 60 sumAll, 61 cntAll
#define THREADS 256
#define STEPS   8

// ---------------------------------------------------------------------------
// Per-element routine. Fast path (bin 29, ~96%): branchless register accum.
// Slow path (d^2 below bin-29 threshold): LDS atomics with the real bin index.
// Boundary-ULP strays that compute idx==29 land in s_sum[29] and are added
// back in the finalize; fast-path bin29 = sumAll - sum(all slow) + s_sum[29].
// ---------------------------------------------------------------------------
__device__ __forceinline__ void ghmr_elem(float pj, float tj, float wj,
                                          float& sumAll, float& cntAll,
                                          float* s_sum, unsigned int* s_cnt)
{
    float d    = pj - tj;
    float d2   = fmaf(d, d, MU2_F);
    float r    = sqrtf(d2);
    float loss = r - MU_F;
    bool valid = wj > 0.0f;
    sumAll += valid ? loss : 0.0f;
    cntAll += valid ? 1.0f : 0.0f;
    if (valid && d2 < T29_F) {
        float g   = fabsf(d) * rsqrtf(d2);
        int   idx = (int)(g * 30.0f);
        idx = idx > BINS - 1 ? BINS - 1 : idx;
        atomicAdd(&s_sum[idx], loss);
        atomicAdd(&s_cnt[idx], 1u);
    }
}

#define GHMR_PROC(P,TT,W) do { \
    ghmr_elem((P).x,(TT).x,(W).x,sumAll,cntAll,s_sum,s_cnt); \
    ghmr_elem((P).y,(TT).y,(W).y,sumAll,cntAll,s_sum,s_cnt); \
    ghmr_elem((P).z,(TT).z,(W).z,sumAll,cntAll,s_sum,s_cnt); \
    ghmr_elem((P).w,(TT).w,(W).w,sumAll,cntAll,s_sum,s_cnt); } while(0)

#define GHMR_TAIL() do { \
    for (int off = 32; off > 0; off >>= 1) { \
        sumAll += __shfl_down(sumAll, off); \
        cntAll += __shfl_down(cntAll, off); \
    } \
    if ((tid & 63) == 0) { atomicAdd(&s_all[0], sumAll); atomicAdd(&s_all[1], cntAll); } \
    __syncthreads(); \
    const int bid = blockIdx.x; \
    if (tid < BINS)            part[tid*pstride + bid] = s_sum[tid]; \
    else if (tid < 2*BINS)     part[tid*pstride + bid] = (float)s_cnt[tid-BINS]; \
    else if (tid == 2*BINS)    part[60*pstride + bid] = s_all[0]; \
    else if (tid == 2*BINS+1)  part[61*pstride + bid] = s_all[1]; } while(0)

// ---------------------------------------------------------------------------
// Fast hist: fully-unrolled 8-step pipeline, per-stream staggered prefetch
// (p: 1 step ahead, t: 2, w: 3) so in-flight requests for the three streams
// sit at different address offsets (channel decorrelation) and ~6 loads/wave
// stay outstanding at all times.
// Requires n4 == gridDim.x * THREADS * STEPS.
// ---------------------------------------------------------------------------
__global__ __launch_bounds__(THREADS) void ghmr_hist_pipe(
    const float4* __restrict__ pred, const float4* __restrict__ target,
    const float4* __restrict__ lw, float* __restrict__ part, int pstride)
{
    __shared__ float        s_sum[BINS];
    __shared__ unsigned int s_cnt[BINS];
    __shared__ float        s_all[2];

    const int tid = threadIdx.x;
    if (tid < BINS) { s_sum[tid] = 0.0f; s_cnt[tid] = 0u; }
    if (tid < 2)    s_all[tid] = 0.0f;
    __syncthreads();

    const int T    = gridDim.x * THREADS;
    const int base = blockIdx.x * THREADS + tid;

    float sumAll = 0.0f, cntAll = 0.0f;

    // prologue: w 3 ahead, t 2 ahead, p 1 ahead
    float4 w0 = lw[base+0*T], w1 = lw[base+1*T], w2 = lw[base+2*T];
    float4 t0 = target[base+0*T], t1 = target[base+1*T];
    float4 p0 = pred[base+0*T];

    float4 p1 = pred[base+1*T]; float4 t2 = target[base+2*T]; float4 w3 = lw[base+3*T];
    GHMR_PROC(p0,t0,w0);
    float4 p2 = pred[base+2*T]; float4 t3 = target[base+3*T]; float4 w4 = lw[base+4*T];
    GHMR_PROC(p1,t1,w1);
    float4 p3 = pred[base+3*T]; float4 t4 = target[base+4*T]; float4 w5 = lw[base+5*T];
    GHMR_PROC(p2,t2,w2);
    float4 p4 = pred[base+4*T]; float4 t5 = target[base+5*T]; float4 w6 = lw[base+6*T];
    GHMR_PROC(p3,t3,w3);
    float4 p5 = pred[base+5*T]; float4 t6 = target[base+6*T]; float4 w7 = lw[base+7*T];
    GHMR_PROC(p4,t4,w4);
    float4 p6 = pred[base+6*T]; float4 t7 = target[base+7*T];
    GHMR_PROC(p5,t5,w5);
    float4 p7 = pred[base+7*T];
    GHMR_PROC(p6,t6,w6);
    GHMR_PROC(p7,t7,w7);

    GHMR_TAIL();
}

// ---------------------------------------------------------------------------
// Generic fallback (any n): grid-stride float4 + scalar tail.
// ---------------------------------------------------------------------------
__global__ __launch_bounds__(THREADS) void ghmr_hist_gen(
    const float* __restrict__ predf, const float* __restrict__ targetf,
    const float* __restrict__ lwf, float* __restrict__ part,
    int pstride, int n)
{
    __shared__ float        s_sum[BINS];
    __shared__ unsigned int s_cnt[BINS];
    __shared__ float        s_all[2];

    const int tid = threadIdx.x;
    if (tid < BINS) { s_sum[tid] = 0.0f; s_cnt[tid] = 0u; }
    if (tid < 2)    s_all[tid] = 0.0f;
    __syncthreads();

    float sumAll = 0.0f, cntAll = 0.0f;

    const int n4 = n / 4;
    const float4* pred   = (const float4*)predf;
    const float4* target = (const float4*)targetf;
    const float4* lw     = (const float4*)lwf;

    for (int i = blockIdx.x*THREADS + tid; i < n4; i += gridDim.x*THREADS) {
        float4 p = pred[i], t = target[i], w = lw[i];
        GHMR_PROC(p,t,w);
    }
    int rem = n - n4*4;
    if (blockIdx.x == 0 && tid < rem) {
        int i = n4*4 + tid;
        ghmr_elem(predf[i], targetf[i], lwf[i], sumAll, cntAll, s_sum, s_cnt);
    }

    GHMR_TAIL();
}

// ---------------------------------------------------------------------------
// Finalize: 16 waves reduce the 62 transposed rows (coalesced), then wave 0
// computes  result = (1/n_nonempty) * sum_b S_b / max(C_b, 1),
// with bin29 reconstructed as (sumAll - sum_slow) + strays.
// ---------------------------------------------------------------------------
__global__ __launch_bounds__(1024) void ghmr_final(
    const float* __restrict__ part, float* __restrict__ out,
    int pstride, int nblk)
{
    __shared__ float red[ROWS];
    const int wv = threadIdx.x >> 6;
    const int ln = threadIdx.x & 63;

    for (int r = wv; r < ROWS; r += 16) {
        float s = 0.0f;
        for (int blk = ln; blk < nblk; blk += 64)
            s += part[r*pstride + blk];
        for (int off = 32; off > 0; off >>= 1) s += __shfl_down(s, off);
        if (ln == 0) red[r] = s;
    }
    __syncthreads();

    if (threadIdx.x < 64) {
        int b = threadIdx.x;
        float Sb = (b < BINS) ? red[b]        : 0.0f;
        float Cb = (b < BINS) ? red[BINS + b] : 0.0f;
        float SS = Sb, CC = Cb;
        for (int off = 1; off < 64; off <<= 1) { SS += __shfl_xor(SS, off); CC += __shfl_xor(CC, off); }
        float SA = red[60], CA = red[61];
        if (b == BINS - 1) { Sb = (SA - SS) + Sb; Cb = (CA - CC) + Cb; }
        float term = (b < BINS) ? Sb / fmaxf(Cb, 1.0f) : 0.0f;
        float nz   = (b < BINS && Cb > 0.0f) ? 1.0f : 0.0f;
        for (int off = 1; off < 64; off <<= 1) { term += __shfl_xor(term, off); nz += __shfl_xor(nz, off); }
        if (b == 0) out[0] = term / fmaxf(nz, 1.0f);
    }
}

// ---------------------------------------------------------------------------
extern "C" void kernel_launch(void* const* d_in, const int* in_sizes, int n_in,
                              void* d_out, int out_size, void* d_ws, size_t ws_size,
                              hipStream_t stream) {
    int n  = in_sizes[0];
    int n4 = n / 4;
    float* part = (float*)d_ws;

    bool fast = (n % 4 == 0) && n4 > 0 &&
                (n4 % (THREADS * STEPS) == 0) &&
                (n4 / (THREADS * STEPS) <= 2048);
    int NB = fast ? n4 / (THREADS * STEPS) : 2048;

    size_t need = (size_t)ROWS * (size_t)NB * sizeof(float);
    if (need > ws_size) {
        fast = false;
        NB = (int)(ws_size / (ROWS * sizeof(float)));
        if (NB > 2048) NB = 2048;
        if (NB < 1) NB = 1;
    }
    int pstride = NB;

    if (fast) {
        ghmr_hist_pipe<<<NB, THREADS, 0, stream>>>(
            (const float4*)d_in[0], (const float4*)d_in[1], (const float4*)d_in[2],
            part, pstride);
    } else {
        ghmr_hist_gen<<<NB, THREADS, 0, stream>>>(
            (const float*)d_in[0], (const float*)d_in[1], (const float*)d_in[2],
            part, pstride, n);
    }
    ghmr_final<<<1, 1024, 0, stream>>>(part, (float*)d_out, pstride, NB);
}

// Round 4
// 44.031 us; speedup vs baseline: 2.0866x; 1.8044x over previous
//
#include <hip/hip_runtime.h>

#define MU_F    0.02f
#define MU2_F   4.0e-4f
// slow-path gate on d2 = d*d + mu2.  True bin-29 boundary: d2 >= mu2*900/59
// = 6.10169e-3.  Use 6.2e-3 (conservative margin): everything below takes the
// exact-bin slow path; fast path is provably bin 29 under fp32 rounding.
#define TSLOW_F 6.2e-3f
#define BINS    30
#define ROWS    62                 // 0..29 sums, 30..59 counts, 60 sumAll, 61 cntAll
#define THREADS 256
#define NBLK    2048

// ---------------------------------------------------------------------------
// Per-element routine. Fast path (bin 29, ~95.5%): branchless register accum.
// Slow path (d2 < TSLOW): LDS atomics with the exact bin index (incl. idx==29
// strays, added back in finalize).
// ---------------------------------------------------------------------------
__device__ __forceinline__ void ghmr_elem(float pj, float tj, float wj,
                                          float& sumAll, float& cntAll,
                                          float* s_sum, unsigned int* s_cnt)
{
    float d    = pj - tj;
    float d2   = fmaf(d, d, MU2_F);
    float loss = sqrtf(d2) - MU_F;
    bool valid = wj > 0.0f;
    sumAll += valid ? loss : 0.0f;
    cntAll += valid ? 1.0f : 0.0f;
    if (valid && d2 < TSLOW_F) {
        float g   = fabsf(d) * rsqrtf(d2);
        int   idx = (int)(g * 30.0f);
        idx = idx > BINS - 1 ? BINS - 1 : idx;
        atomicAdd(&s_sum[idx], loss);
        atomicAdd(&s_cnt[idx], 1u);
    }
}

#define GHMR_PROC(P,TT,W) do { \
    ghmr_elem((P).x,(TT).x,(W).x,sumAll,cntAll,s_sum,s_cnt); \
    ghmr_elem((P).y,(TT).y,(W).y,sumAll,cntAll,s_sum,s_cnt); \
    ghmr_elem((P).z,(TT).z,(W).z,sumAll,cntAll,s_sum,s_cnt); \
    ghmr_elem((P).w,(TT).w,(W).w,sumAll,cntAll,s_sum,s_cnt); } while(0)

#define GHMR_TAIL() do { \
    for (int off = 32; off > 0; off >>= 1) { \
        sumAll += __shfl_down(sumAll, off); \
        cntAll += __shfl_down(cntAll, off); \
    } \
    if ((tid & 63) == 0) { atomicAdd(&s_all[0], sumAll); atomicAdd(&s_all[1], cntAll); } \
    __syncthreads(); \
    const int bid = blockIdx.x; \
    if (tid < BINS)            part[tid*pstride + bid] = s_sum[tid]; \
    else if (tid < 2*BINS)     part[tid*pstride + bid] = (float)s_cnt[tid-BINS]; \
    else if (tid == 2*BINS)    part[60*pstride + bid] = s_all[0]; \
    else if (tid == 2*BINS+1)  part[61*pstride + bid] = s_all[1]; } while(0)

// ---------------------------------------------------------------------------
// Chunked hist: each thread owns 4 consecutive float4s (64B) per stream per
// iteration. One wave instruction spans 4KB contiguous per stream (DRAM-burst
// friendly); 12 loads issued before compute (sched_barrier blocks sinking).
// Requires n % 16 == 0; nchunks = n/16.
// ---------------------------------------------------------------------------
__global__ __launch_bounds__(THREADS, 4) void ghmr_hist_chunk(
    const float4* __restrict__ pred, const float4* __restrict__ target,
    const float4* __restrict__ lw, float* __restrict__ part,
    int pstride, int nchunks)
{
    __shared__ float        s_sum[BINS];
    __shared__ unsigned int s_cnt[BINS];
    __shared__ float        s_all[2];

    const int tid = threadIdx.x;
    if (tid < BINS) { s_sum[tid] = 0.0f; s_cnt[tid] = 0u; }
    if (tid < 2)    s_all[tid] = 0.0f;
    __syncthreads();

    float sumAll = 0.0f, cntAll = 0.0f;

    const int G = gridDim.x * THREADS;
    for (int g = blockIdx.x * THREADS + tid; g < nchunks; g += G) {
        const int b = 4 * g;
        float4 p0 = pred[b+0], p1 = pred[b+1], p2 = pred[b+2], p3 = pred[b+3];
        float4 t0 = target[b+0], t1 = target[b+1], t2 = target[b+2], t3 = target[b+3];
        float4 w0 = lw[b+0], w1 = lw[b+1], w2 = lw[b+2], w3 = lw[b+3];
        __builtin_amdgcn_sched_barrier(0);   // issue all 12 loads before compute
        GHMR_PROC(p0,t0,w0);
        GHMR_PROC(p1,t1,w1);
        GHMR_PROC(p2,t2,w2);
        GHMR_PROC(p3,t3,w3);
    }

    GHMR_TAIL();
}

// ---------------------------------------------------------------------------
// Generic fallback (any n): grid-stride float4 + scalar tail.
// ---------------------------------------------------------------------------
__global__ __launch_bounds__(THREADS) void ghmr_hist_gen(
    const float* __restrict__ predf, const float* __restrict__ targetf,
    const float* __restrict__ lwf, float* __restrict__ part,
    int pstride, int n)
{
    __shared__ float        s_sum[BINS];
    __shared__ unsigned int s_cnt[BINS];
    __shared__ float        s_all[2];

    const int tid = threadIdx.x;
    if (tid < BINS) { s_sum[tid] = 0.0f; s_cnt[tid] = 0u; }
    if (tid < 2)    s_all[tid] = 0.0f;
    __syncthreads();

    float sumAll = 0.0f, cntAll = 0.0f;

    const int n4 = n / 4;
    const float4* pred   = (const float4*)predf;
    const float4* target = (const float4*)targetf;
    const float4* lw     = (const float4*)lwf;

    for (int i = blockIdx.x*THREADS + tid; i < n4; i += gridDim.x*THREADS) {
        float4 p = pred[i], t = target[i], w = lw[i];
        GHMR_PROC(p,t,w);
    }
    int rem = n - n4*4;
    if (blockIdx.x == 0 && tid < rem) {
        int i = n4*4 + tid;
        ghmr_elem(predf[i], targetf[i], lwf[i], sumAll, cntAll, s_sum, s_cnt);
    }

    GHMR_TAIL();
}

// ---------------------------------------------------------------------------
// Reduce stage 1: 62 blocks, one transposed row each; coalesced, all CUs busy.
// ---------------------------------------------------------------------------
__global__ __launch_bounds__(256) void ghmr_reduce(
    const float* __restrict__ part, float* __restrict__ red,
    int pstride, int nblk)
{
    const int r = blockIdx.x;          // 0..ROWS-1
    float s = 0.0f;
    for (int i = threadIdx.x; i < nblk; i += 256)
        s += part[r*pstride + i];
    __shared__ float ls[4];
    for (int off = 32; off > 0; off >>= 1) s += __shfl_down(s, off);
    if ((threadIdx.x & 63) == 0) ls[threadIdx.x >> 6] = s;
    __syncthreads();
    if (threadIdx.x == 0) red[r] = ls[0] + ls[1] + ls[2] + ls[3];
}

// ---------------------------------------------------------------------------
// Finalize: result = (1/n_nonempty) * sum_b S_b / max(C_b, 1),
// with bin29 reconstructed as (sumAll - sum_slow) + idx==29 strays.
// ---------------------------------------------------------------------------
__global__ void ghmr_final(const float* __restrict__ red, float* __restrict__ out)
{
    int b = threadIdx.x;   // 0..63
    float Sb = (b < BINS) ? red[b]        : 0.0f;
    float Cb = (b < BINS) ? red[BINS + b] : 0.0f;
    float SS = Sb, CC = Cb;
    for (int off = 1; off < 64; off <<= 1) { SS += __shfl_xor(SS, off); CC += __shfl_xor(CC, off); }
    float SA = red[60], CA = red[61];
    if (b == BINS - 1) { Sb = (SA - SS) + Sb; Cb = (CA - CC) + Cb; }
    float term = (b < BINS) ? Sb / fmaxf(Cb, 1.0f) : 0.0f;
    float nz   = (b < BINS && Cb > 0.0f) ? 1.0f : 0.0f;
    for (int off = 1; off < 64; off <<= 1) { term += __shfl_xor(term, off); nz += __shfl_xor(nz, off); }
    if (b == 0) out[0] = term / fmaxf(nz, 1.0f);
}

// ---------------------------------------------------------------------------
extern "C" void kernel_launch(void* const* d_in, const int* in_sizes, int n_in,
                              void* d_out, int out_size, void* d_ws, size_t ws_size,
                              hipStream_t stream) {
    int n = in_sizes[0];

    int NB = NBLK;
    size_t need = (size_t)ROWS * (size_t)NB * sizeof(float) + ROWS * sizeof(float);
    bool ws_ok = need <= ws_size;
    if (!ws_ok) {
        NB = (int)((ws_size / sizeof(float) - ROWS) / ROWS);
        if (NB > NBLK) NB = NBLK;
        if (NB < 1) NB = 1;
    }
    int pstride = NB;
    float* part = (float*)d_ws;                  // [ROWS][pstride]
    float* red  = part + (size_t)ROWS * pstride; // [ROWS]

    bool fast = ws_ok && (n % 16 == 0) && n > 0;

    if (fast) {
        int nchunks = n / 16;
        ghmr_hist_chunk<<<NB, THREADS, 0, stream>>>(
            (const float4*)d_in[0], (const float4*)d_in[1], (const float4*)d_in[2],
            part, pstride, nchunks);
    } else {
        ghmr_hist_gen<<<NB, THREADS, 0, stream>>>(
            (const float*)d_in[0], (const float*)d_in[1], (const float*)d_in[2],
            part, pstride, n);
    }
    ghmr_reduce<<<ROWS, 256, 0, stream>>>(part, red, pstride, NB);
    ghmr_final<<<1, 64, 0, stream>>>(red, (float*)d_out);
}